// Round 6
// baseline (622.290 us; speedup 1.0000x reference)
//
#include <hip/hip_runtime.h>

// ---------------------------------------------------------------------------
// FGSW-MSA, round 6 == round 5 + pls pad-column zeroing (NaN x 0 = NaN fix).
//  - q-conv split into standalone big-tile MFMA kernel writing into the SAME
//    buffer attention later writes (qc == ao, px-for-px aliasing; safe because
//    each window block reads its own qc[h] strictly before writing ao[h], and
//    ao writes are deferred one phase).
//  - fused kernel: LDS 35.7 KB -> 4 blocks/CU; 2 barriers/head; redundant QK
//    in all 4 waves + in-register softmax; stride-80 patch (2-way banks).
//
// ws layout (bytes):
//   qn   (2,128,128,64)  bf16 @ 0           4,194,304
//   kvn  (6,128,128,64)  bf16 @ 4,194,304   12,582,912
//   qcao (2,128,128,512) bf16 @ 16,777,216  33,554,432   (q-conv out == attn out)
//   wq   (512,576)  bf16      @ 50,331,648    589,824
//   wkv  (1024,576) bf16      @ 50,921,472  1,179,648
//   wop  (64,4608)  bf16      @ 52,101,120    589,824
// total 52,690,944 B
// ---------------------------------------------------------------------------

typedef __attribute__((ext_vector_type(8))) short bf16x8;
typedef __attribute__((ext_vector_type(4))) float f32x4;

__device__ __forceinline__ float bs2f(unsigned short s) {
    return __uint_as_float(((unsigned int)s) << 16);
}
__device__ __forceinline__ unsigned short f2bs(float f) {
    unsigned int u = __float_as_uint(f);
    u += 0x7fffu + ((u >> 16) & 1u);   // RNE
    return (unsigned short)(u >> 16);
}

// ------------------------- LayerNorm (q path) ------------------------------
__global__ __launch_bounds__(256) void ln_q_kernel(
    const float* __restrict__ q_inp, const float* __restrict__ g,
    const float* __restrict__ b, unsigned short* __restrict__ qn)
{
    int wid  = (blockIdx.x * 256 + threadIdx.x) >> 6;
    int lane = threadIdx.x & 63;
    int pix  = wid & 16383;
    int bb   = wid >> 14;
    float val = q_inp[(bb * 64 + lane) * 16384 + pix];
    float s = val;
    #pragma unroll
    for (int m = 1; m < 64; m <<= 1) s += __shfl_xor(s, m);
    float mu = s * (1.f / 64.f);
    float d = val - mu;
    float s2 = d * d;
    #pragma unroll
    for (int m = 1; m < 64; m <<= 1) s2 += __shfl_xor(s2, m);
    float o = d * rsqrtf(s2 * (1.f / 64.f) + 1e-5f) * g[lane] + b[lane];
    qn[wid * 64 + lane] = f2bs(o);
}

// --------------------- nearest-warp + LayerNorm (kv path) ------------------
__global__ __launch_bounds__(256) void warp_ln_kv_kernel(
    const float* __restrict__ k_inp, const float* __restrict__ flow_f,
    const float* __restrict__ flow_b, const float* __restrict__ g,
    const float* __restrict__ b, unsigned short* __restrict__ kvn)
{
    int wid  = (blockIdx.x * 256 + threadIdx.x) >> 6;
    int lane = threadIdx.x & 63;
    int x  = wid & 127;
    int y  = (wid >> 7) & 127;
    int bf = wid >> 14;
    int f  = bf % 3, bb = bf / 3;
    float val;
    if (f == 1) {
        val = k_inp[(bf * 64 + lane) * 16384 + y * 128 + x];
    } else {
        const float* fl = (f == 0) ? flow_f : flow_b;
        float fx = fl[(bb * 2 + 0) * 16384 + y * 128 + x];
        float fy = fl[(bb * 2 + 1) * 16384 + y * 128 + x];
        int ix = (int)rintf((float)x + fx);
        int iy = (int)rintf((float)y + fy);
        if (ix >= 0 && ix < 128 && iy >= 0 && iy < 128)
            val = k_inp[(bf * 64 + lane) * 16384 + iy * 128 + ix];
        else
            val = 0.f;
    }
    float s = val;
    #pragma unroll
    for (int m = 1; m < 64; m <<= 1) s += __shfl_xor(s, m);
    float mu = s * (1.f / 64.f);
    float d = val - mu;
    float s2 = d * d;
    #pragma unroll
    for (int m = 1; m < 64; m <<= 1) s2 += __shfl_xor(s2, m);
    float o = d * rsqrtf(s2 * (1.f / 64.f) + 1e-5f) * g[lane] + b[lane];
    kvn[wid * 64 + lane] = f2bs(o);
}

// --------------------------- weight repack (f32 -> bf16) --------------------
// src (OC, IC, 3, 3); dst[oc][ (ic/64)*576 + tap*64 + (ic%64) ]
__global__ __launch_bounds__(256) void repack_bf16_kernel(
    const float* __restrict__ w, unsigned short* __restrict__ wp,
    int IC, int total)
{
    int idx = blockIdx.x * 256 + threadIdx.x;
    if (idx >= total) return;
    int tap = idx % 9;
    int tmp = idx / 9;
    int ic  = tmp % IC;
    int oc  = tmp / IC;
    wp[oc * IC * 9 + (ic >> 6) * 576 + tap * 64 + (ic & 63)] = f2bs(w[idx]);
}

// --------------------- standalone q conv (3x3, 64->512) --------------------
// 512 thr = 8 waves; 8x8 px tile; wave = (M-tile m = w>>1, N-half nh = w&1).
// Output scaled 1/8, bf16, into qcao (aliased with attention output).
__global__ __launch_bounds__(512) void qconv_kernel(
    const unsigned short* __restrict__ qn,
    const unsigned short* __restrict__ wq,    // (512, 576) bf16
    unsigned short* __restrict__ qc)
{
    __shared__ __align__(16) unsigned short patch[100 * 80];
    const int tid = threadIdx.x, lane = tid & 63, w = tid >> 6;
    const int tx = blockIdx.x & 15, ty = blockIdx.x >> 4;
    const int img = blockIdx.y;
    const int gx0 = tx * 8 - 1, gy0 = ty * 8 - 1;
    const int r = lane & 15, kg = lane >> 4;
    const int m = w >> 1, nh = w & 1;

    for (int u = tid; u < 800; u += 512) {
        int pos = u >> 3, seg = u & 7;
        int hy = pos / 10, hx = pos - hy * 10;
        int gy = gy0 + hy, gx = gx0 + hx;
        uint4 v = make_uint4(0u, 0u, 0u, 0u);
        if ((unsigned)gy < 128u && (unsigned)gx < 128u)
            v = *reinterpret_cast<const uint4*>(
                qn + ((img * 128 + gy) * 128 + gx) * 64 + seg * 8);
        *reinterpret_cast<uint4*>(patch + pos * 80 + seg * 8) = v;
    }
    __syncthreads();

    f32x4 acc[16];
    #pragma unroll
    for (int n = 0; n < 16; ++n) acc[n] = f32x4{0.f, 0.f, 0.f, 0.f};

    #pragma unroll 2
    for (int kk = 0; kk < 18; ++kk) {
        int tap = kk >> 1, ic0 = (kk & 1) * 32;
        int ky = tap / 3, kx = tap - ky * 3;
        int pos = (m * 2 + (r >> 3) + ky) * 10 + (r & 7) + kx;
        bf16x8 a = *reinterpret_cast<const bf16x8*>(patch + pos * 80 + ic0 + kg * 8);
        #pragma unroll
        for (int n = 0; n < 16; ++n) {
            bf16x8 b = *reinterpret_cast<const bf16x8*>(
                wq + (size_t)(nh * 256 + n * 16 + r) * 576 + kk * 32 + kg * 8);
            acc[n] = __builtin_amdgcn_mfma_f32_16x16x32_bf16(a, b, acc[n], 0, 0, 0);
        }
    }
    #pragma unroll
    for (int n = 0; n < 16; ++n) {
        #pragma unroll
        for (int reg = 0; reg < 4; ++reg) {
            int p = m * 16 + kg * 4 + reg;
            int y = ty * 8 + (p >> 3), x = tx * 8 + (p & 7);
            qc[((size_t)(img * 128 + y) * 128 + x) * 512 + nh * 256 + n * 16 + r] =
                f2bs(0.125f * acc[n][reg]);
        }
    }
}

// ----------------- fused conv_kv + window attention ------------------------
// grid (1024, 2). 256 thr = 4 waves.  LDS 35,712 B -> 4 blocks/CU.
//   kvp   u16[3][36][80] @ 0      (17,280)
//   kls   u16[48][72]    @ 17,280 ( 6,912)
//   vls_T u16[64][72]    @ 24,192 ( 9,216)  cols 48..63 zeroed once
//   pls   u16[16][72]    @ 33,408 ( 2,304)  cols 48..63 zeroed once (NaN x 0 fix)
__global__ __launch_bounds__(256, 4) void fused_attn_kernel(
    const unsigned short* __restrict__ kvn,
    const unsigned short* __restrict__ wkv,
    const float* __restrict__ sa,
    unsigned short* __restrict__ qcao)
{
    __shared__ __align__(16) unsigned char smem[35712];
    unsigned short* kvp   = (unsigned short*)smem;
    unsigned short* kls   = (unsigned short*)(smem + 17280);
    unsigned short* vls_T = (unsigned short*)(smem + 24192);
    unsigned short* pls   = (unsigned short*)(smem + 33408);

    const int tid  = threadIdx.x;
    const int lane = tid & 63;
    const int w    = tid >> 6;
    const int wx = blockIdx.x & 31, wy = blockIdx.x >> 5;
    const int bb = blockIdx.y;
    const int gx0 = wx * 4 - 1, gy0 = wy * 4 - 1;

    // ---- stage kv halo patches (stride 80) ----
    for (int u = tid; u < 864; u += 256) {
        int f = u / 288, rest = u - f * 288;
        int pos = rest >> 3, seg = rest & 7;
        int hy = pos / 6, hx = pos - hy * 6;
        int gy = gy0 + hy, gx = gx0 + hx;
        uint4 v = make_uint4(0u, 0u, 0u, 0u);
        if ((unsigned)gy < 128u && (unsigned)gx < 128u)
            v = *reinterpret_cast<const uint4*>(
                kvn + (((bb * 3 + f) * 128 + gy) * 128 + gx) * 64 + seg * 8);
        *reinterpret_cast<uint4*>(kvp + (f * 36 + pos) * 80 + seg * 8) = v;
    }
    // ---- zero vls_T pad cols 48..63 (once; conv only writes cols 0..47) ----
    for (int u = tid; u < 1024; u += 256) {
        int row = u >> 4, c = 48 + (u & 15);
        vls_T[row * 72 + c] = 0;
    }
    // ---- zero pls pad cols 48..63 (once; softmax writes only cols 0..47).
    //      PV reads these as A-operand k=48..63; garbage here can be NaN/Inf
    //      and NaN*0 = NaN even though the matching vls_T cols are zero. ----
    {
        int row = tid >> 4, c = 48 + (tid & 15);
        pls[row * 72 + c] = 0;
    }
    __syncthreads();

    const int r  = lane & 15;
    const int kg = lane >> 4;
    const int py = r >> 2, px = r & 3;
    const int is_v = w >> 1, pair = w & 1;

    // q-row global base for this lane's QK A-fragment (row = px index r)
    const unsigned short* qbase =
        qcao + ((size_t)(bb * 128 + wy * 4 + (r >> 2)) * 128 + wx * 4 + (r & 3)) * 512;

    f32x4 oacc = {0.f, 0.f, 0.f, 0.f};

    for (int h = 0; h < 8; ++h) {
        // ---- deferred ao write of head h-1 (no reader of these cols remains) ----
        if (h > 0) {
            #pragma unroll
            for (int reg = 0; reg < 4; ++reg) {
                int i = kg * 4 + reg;
                int y = wy * 4 + (i >> 2), x = wx * 4 + (i & 3);
                qcao[((size_t)(bb * 128 + y) * 128 + x) * 512 + (h - 1) * 64 + w * 16 + r] =
                    f2bs(oacc[reg]);
            }
        }

        // ---- conv k,v for this head (waves 0,1 -> k; 2,3 -> v transposed) ----
        {
            const int ocb = is_v * 512 + h * 64 + pair * 32;
            const unsigned short* wb = wkv + (size_t)ocb * 576 + kg * 8;
            bf16x8 nb0 = *reinterpret_cast<const bf16x8*>(wb + (size_t)r * 576);
            bf16x8 nb1 = *reinterpret_cast<const bf16x8*>(wb + (size_t)(16 + r) * 576);
            f32x4 c00 = {0.f,0.f,0.f,0.f}, c01 = c00, c10 = c00, c11 = c00, c20 = c00, c21 = c00;
            #pragma unroll 2
            for (int kk = 0; kk < 18; ++kk) {
                bf16x8 b0 = nb0, b1 = nb1;
                if (kk < 17) {
                    nb0 = *reinterpret_cast<const bf16x8*>(wb + (size_t)r * 576 + (kk + 1) * 32);
                    nb1 = *reinterpret_cast<const bf16x8*>(wb + (size_t)(16 + r) * 576 + (kk + 1) * 32);
                }
                int tap = kk >> 1, ic0 = (kk & 1) * 32;
                int ky = tap / 3, kx = tap - ky * 3;
                int pos = (py + ky) * 6 + (px + kx);
                bf16x8 a0 = *reinterpret_cast<const bf16x8*>(kvp + pos * 80 + ic0 + kg * 8);
                bf16x8 a1 = *reinterpret_cast<const bf16x8*>(kvp + (36 + pos) * 80 + ic0 + kg * 8);
                bf16x8 a2 = *reinterpret_cast<const bf16x8*>(kvp + (72 + pos) * 80 + ic0 + kg * 8);
                c00 = __builtin_amdgcn_mfma_f32_16x16x32_bf16(a0, b0, c00, 0, 0, 0);
                c10 = __builtin_amdgcn_mfma_f32_16x16x32_bf16(a1, b0, c10, 0, 0, 0);
                c20 = __builtin_amdgcn_mfma_f32_16x16x32_bf16(a2, b0, c20, 0, 0, 0);
                c01 = __builtin_amdgcn_mfma_f32_16x16x32_bf16(a0, b1, c01, 0, 0, 0);
                c11 = __builtin_amdgcn_mfma_f32_16x16x32_bf16(a1, b1, c11, 0, 0, 0);
                c21 = __builtin_amdgcn_mfma_f32_16x16x32_bf16(a2, b1, c21, 0, 0, 0);
            }
            if (!is_v) {
                #pragma unroll
                for (int reg = 0; reg < 4; ++reg) {
                    int jr = kg * 4 + reg;
                    int cb = pair * 32 + r;
                    kls[(jr +  0) * 72 + cb]      = f2bs(c00[reg]);
                    kls[(jr + 16) * 72 + cb]      = f2bs(c10[reg]);
                    kls[(jr + 32) * 72 + cb]      = f2bs(c20[reg]);
                    kls[(jr +  0) * 72 + cb + 16] = f2bs(c01[reg]);
                    kls[(jr + 16) * 72 + cb + 16] = f2bs(c11[reg]);
                    kls[(jr + 32) * 72 + cb + 16] = f2bs(c21[reg]);
                }
            } else {
                #pragma unroll
                for (int reg = 0; reg < 4; ++reg) {
                    int jr = kg * 4 + reg;
                    int d0 = pair * 32 + r;
                    vls_T[d0 * 72        + jr]      = f2bs(c00[reg]);
                    vls_T[d0 * 72        + 16 + jr] = f2bs(c10[reg]);
                    vls_T[d0 * 72        + 32 + jr] = f2bs(c20[reg]);
                    vls_T[(d0 + 16) * 72 + jr]      = f2bs(c01[reg]);
                    vls_T[(d0 + 16) * 72 + 16 + jr] = f2bs(c11[reg]);
                    vls_T[(d0 + 16) * 72 + 32 + jr] = f2bs(c21[reg]);
                }
            }
        }
        __syncthreads();

        // ---- QK^T (redundant in all 4 waves) + in-register softmax ----
        {
            bf16x8 qa0 = *reinterpret_cast<const bf16x8*>(qbase + h * 64 + kg * 8);
            bf16x8 qa1 = *reinterpret_cast<const bf16x8*>(qbase + h * 64 + 32 + kg * 8);
            f32x4 s0 = {0.f,0.f,0.f,0.f}, s1 = s0, s2 = s0;
            #pragma unroll
            for (int t = 0; t < 3; ++t) {
                bf16x8 b0 = *reinterpret_cast<const bf16x8*>(kls + (t * 16 + r) * 72 + kg * 8);
                bf16x8 b1 = *reinterpret_cast<const bf16x8*>(kls + (t * 16 + r) * 72 + 32 + kg * 8);
                f32x4& st = (t == 0) ? s0 : (t == 1) ? s1 : s2;
                st = __builtin_amdgcn_mfma_f32_16x16x32_bf16(qa0, b0, st, 0, 0, 0);
                st = __builtin_amdgcn_mfma_f32_16x16x32_bf16(qa1, b1, st, 0, 0, 0);
            }
            // add static_a; row-wise softmax (row = kg*4+reg, cols t*16+r over 16 r-lanes)
            #pragma unroll
            for (int reg = 0; reg < 4; ++reg) {
                int i = kg * 4 + reg;
                float v0 = s0[reg] + sa[(h * 16 + i) * 48 + r];
                float v1 = s1[reg] + sa[(h * 16 + i) * 48 + 16 + r];
                float v2 = s2[reg] + sa[(h * 16 + i) * 48 + 32 + r];
                float mx = fmaxf(v0, fmaxf(v1, v2));
                #pragma unroll
                for (int m = 1; m < 16; m <<= 1) mx = fmaxf(mx, __shfl_xor(mx, m));
                float e0 = __expf(v0 - mx), e1 = __expf(v1 - mx), e2 = __expf(v2 - mx);
                float sum = e0 + e1 + e2;
                #pragma unroll
                for (int m = 1; m < 16; m <<= 1) sum += __shfl_xor(sum, m);
                float inv = 1.f / sum;
                pls[i * 72 + r]      = f2bs(e0 * inv);
                pls[i * 72 + 16 + r] = f2bs(e1 * inv);
                pls[i * 72 + 32 + r] = f2bs(e2 * inv);
            }
        }
        // own wave wrote every pls row it reads below; compiler inserts lgkmcnt.

        // ---- PV: wave w owns d-tile w (cols d = w*16 + r) ----
        {
            bf16x8 pa0 = *reinterpret_cast<const bf16x8*>(pls + r * 72 + kg * 8);
            bf16x8 pa1 = *reinterpret_cast<const bf16x8*>(pls + r * 72 + 32 + kg * 8);
            bf16x8 vb0 = *reinterpret_cast<const bf16x8*>(vls_T + (w * 16 + r) * 72 + kg * 8);
            bf16x8 vb1 = *reinterpret_cast<const bf16x8*>(vls_T + (w * 16 + r) * 72 + 32 + kg * 8);
            f32x4 o = {0.f, 0.f, 0.f, 0.f};
            o = __builtin_amdgcn_mfma_f32_16x16x32_bf16(pa0, vb0, o, 0, 0, 0);
            o = __builtin_amdgcn_mfma_f32_16x16x32_bf16(pa1, vb1, o, 0, 0, 0);
            oacc = o;   // deferred store at top of next phase
        }
        __syncthreads();   // protect kls/vls_T/pls before next head's conv
    }
    // ---- final head's output ----
    #pragma unroll
    for (int reg = 0; reg < 4; ++reg) {
        int i = kg * 4 + reg;
        int y = wy * 4 + (i >> 2), x = wx * 4 + (i & 3);
        qcao[((size_t)(bb * 128 + y) * 128 + x) * 512 + 7 * 64 + w * 16 + r] = f2bs(oacc[reg]);
    }
}

// --------------- 3x3 conv, IC=512 -> OC=64 via MFMA (out conv) -------------
__global__ __launch_bounds__(256) void conv512_kernel(
    const unsigned short* __restrict__ in,
    const unsigned short* __restrict__ wp,    // (64, 4608) bf16
    float* __restrict__ out)
{
    __shared__ __align__(16) unsigned short patch[100 * 80];
    const int tid = threadIdx.x, lane = tid & 63, w = tid >> 6;
    const int tx = blockIdx.x & 15, ty = blockIdx.x >> 4;
    const int img = blockIdx.y;
    const int gx0 = tx * 8 - 1, gy0 = ty * 8 - 1;
    const int r = lane & 15, kg = lane >> 4;

    f32x4 acc0 = {0.f,0.f,0.f,0.f}, acc1 = acc0, acc2 = acc0, acc3 = acc0;

    for (int ci = 0; ci < 8; ++ci) {
        __syncthreads();
        for (int u = tid; u < 800; u += 256) {
            int pos = u >> 3, seg = u & 7;
            int hy = pos / 10, hx = pos - hy * 10;
            int gy = gy0 + hy, gx = gx0 + hx;
            uint4 v = make_uint4(0u, 0u, 0u, 0u);
            if ((unsigned)gy < 128u && (unsigned)gx < 128u)
                v = *reinterpret_cast<const uint4*>(
                    in + (((size_t)img * 128 + gy) * 128 + gx) * 512 + ci * 64 + seg * 8);
            *reinterpret_cast<uint4*>(patch + pos * 80 + seg * 8) = v;
        }
        __syncthreads();
        #pragma unroll 3
        for (int kk = 0; kk < 18; ++kk) {
            int tap = kk >> 1, ic0 = (kk & 1) * 32;
            int ky = tap / 3, kx = tap - ky * 3;
            int oc = w * 16 + r;
            bf16x8 b = *reinterpret_cast<const bf16x8*>(
                wp + (size_t)oc * 4608 + ci * 576 + kk * 32 + kg * 8);
            #pragma unroll
            for (int m = 0; m < 4; ++m) {
                int rr = m * 16 + r;
                int pos = ((rr >> 3) + ky) * 10 + (rr & 7) + kx;
                bf16x8 a = *reinterpret_cast<const bf16x8*>(patch + pos * 80 + ic0 + kg * 8);
                f32x4& acc = (m == 0) ? acc0 : (m == 1) ? acc1 : (m == 2) ? acc2 : acc3;
                acc = __builtin_amdgcn_mfma_f32_16x16x32_bf16(a, b, acc, 0, 0, 0);
            }
        }
    }
    const int oc = w * 16 + r;
    #pragma unroll
    for (int m = 0; m < 4; ++m) {
        const f32x4& acc = (m == 0) ? acc0 : (m == 1) ? acc1 : (m == 2) ? acc2 : acc3;
        int r0 = m * 16 + kg * 4;
        int gy = ty * 8 + (r0 >> 3), gx = tx * 8 + (r0 & 7);
        *reinterpret_cast<float4*>(
            out + (((size_t)img * 64 + oc) * 128 + gy) * 128 + gx) =
            make_float4(acc[0], acc[1], acc[2], acc[3]);
    }
}

// ---------------------------------------------------------------------------
extern "C" void kernel_launch(void* const* d_in, const int* in_sizes, int n_in,
                              void* d_out, int out_size, void* d_ws, size_t ws_size,
                              hipStream_t stream)
{
    const float* q_inp  = (const float*)d_in[0];
    const float* k_inp  = (const float*)d_in[1];
    const float* flow_f = (const float*)d_in[2];
    const float* flow_b = (const float*)d_in[3];
    const float* gq     = (const float*)d_in[4];
    const float* bq     = (const float*)d_in[5];
    const float* gkv    = (const float*)d_in[6];
    const float* bkv    = (const float*)d_in[7];
    const float* Wq     = (const float*)d_in[8];
    const float* Wkv    = (const float*)d_in[9];
    const float* Wout   = (const float*)d_in[10];
    const float* sa     = (const float*)d_in[11];

    if (ws_size < 55050240u) return;

    char* ws = (char*)d_ws;
    unsigned short* qn   = (unsigned short*)(ws + 0);
    unsigned short* kvn  = (unsigned short*)(ws + 4194304);
    unsigned short* qcao = (unsigned short*)(ws + 16777216);
    unsigned short* wqb  = (unsigned short*)(ws + 50331648);
    unsigned short* wkvb = (unsigned short*)(ws + 50921472);
    unsigned short* wopb = (unsigned short*)(ws + 52101120);

    ln_q_kernel<<<8192, 256, 0, stream>>>(q_inp, gq, bq, qn);
    warp_ln_kv_kernel<<<24576, 256, 0, stream>>>(k_inp, flow_f, flow_b, gkv, bkv, kvn);

    repack_bf16_kernel<<<1152, 256, 0, stream>>>(Wq,   wqb,  64,  294912);
    repack_bf16_kernel<<<2304, 256, 0, stream>>>(Wkv,  wkvb, 64,  589824);
    repack_bf16_kernel<<<1152, 256, 0, stream>>>(Wout, wopb, 512, 294912);

    qconv_kernel<<<dim3(256, 2), 512, 0, stream>>>(qn, wqb, qcao);

    fused_attn_kernel<<<dim3(1024, 2), 256, 0, stream>>>(kvn, wkvb, sa, qcao);

    conv512_kernel<<<dim3(256, 2), 256, 0, stream>>>(qcao, wopb, (float*)d_out);
}

// Round 7
// 608.561 us; speedup vs baseline: 1.0226x; 1.0226x over previous
//
#include <hip/hip_runtime.h>

// ---------------------------------------------------------------------------
// FGSW-MSA, round 7 = round 6 + latency surgery:
//  - kvp/patch LDS stride 80 -> 88 u16 (bank stride 12: ~2-way conflicts)
//  - depth-2 weight prefetch in fused conv + conv512 (static regs)
//  - q-fragment prefetch (next head) + sa early-issue in fused
//  - ln_q + warp_ln_kv fused into one kernel; 3 repacks into one kernel
//
// ws layout (bytes):
//   qn   (2,128,128,64)  bf16 @ 0           4,194,304
//   kvn  (6,128,128,64)  bf16 @ 4,194,304   12,582,912
//   qcao (2,128,128,512) bf16 @ 16,777,216  33,554,432   (q-conv out == attn out)
//   wq   (512,576)  bf16      @ 50,331,648    589,824
//   wkv  (1024,576) bf16      @ 50,921,472  1,179,648
//   wop  (64,4608)  bf16      @ 52,101,120    589,824
// ---------------------------------------------------------------------------

typedef __attribute__((ext_vector_type(8))) short bf16x8;
typedef __attribute__((ext_vector_type(4))) float f32x4;

__device__ __forceinline__ float bs2f(unsigned short s) {
    return __uint_as_float(((unsigned int)s) << 16);
}
__device__ __forceinline__ unsigned short f2bs(float f) {
    unsigned int u = __float_as_uint(f);
    u += 0x7fffu + ((u >> 16) & 1u);   // RNE
    return (unsigned short)(u >> 16);
}

// --------------- fused LayerNorm (q) + warp+LayerNorm (kv) -----------------
// wid 0..32767: q path.  wid 32768..131071: kv path.
__global__ __launch_bounds__(256) void ln_all_kernel(
    const float* __restrict__ q_inp, const float* __restrict__ k_inp,
    const float* __restrict__ flow_f, const float* __restrict__ flow_b,
    const float* __restrict__ gq, const float* __restrict__ bq,
    const float* __restrict__ gkv, const float* __restrict__ bkv,
    unsigned short* __restrict__ qn, unsigned short* __restrict__ kvn)
{
    int wid  = (blockIdx.x * 256 + threadIdx.x) >> 6;
    int lane = threadIdx.x & 63;
    float val, gg, bbv;
    unsigned short* dst;
    if (wid < 32768) {
        int pix = wid & 16383, bb = wid >> 14;
        val = q_inp[(bb * 64 + lane) * 16384 + pix];
        gg = gq[lane]; bbv = bq[lane];
        dst = qn + wid * 64 + lane;
    } else {
        int kw = wid - 32768;
        int x = kw & 127, y = (kw >> 7) & 127, bf = kw >> 14;
        int f = bf % 3, bb = bf / 3;
        if (f == 1) {
            val = k_inp[(bf * 64 + lane) * 16384 + y * 128 + x];
        } else {
            const float* fl = (f == 0) ? flow_f : flow_b;
            float fx = fl[(bb * 2 + 0) * 16384 + y * 128 + x];
            float fy = fl[(bb * 2 + 1) * 16384 + y * 128 + x];
            int ix = (int)rintf((float)x + fx);
            int iy = (int)rintf((float)y + fy);
            if (ix >= 0 && ix < 128 && iy >= 0 && iy < 128)
                val = k_inp[(bf * 64 + lane) * 16384 + iy * 128 + ix];
            else
                val = 0.f;
        }
        gg = gkv[lane]; bbv = bkv[lane];
        dst = kvn + kw * 64 + lane;
    }
    float s = val;
    #pragma unroll
    for (int m = 1; m < 64; m <<= 1) s += __shfl_xor(s, m);
    float mu = s * (1.f / 64.f);
    float d = val - mu;
    float s2 = d * d;
    #pragma unroll
    for (int m = 1; m < 64; m <<= 1) s2 += __shfl_xor(s2, m);
    *dst = f2bs(d * rsqrtf(s2 * (1.f / 64.f) + 1e-5f) * gg + bbv);
}

// --------------------------- weight repack (all three) ---------------------
// dst[oc][ (ic/64)*576 + tap*64 + (ic%64) ]
__device__ __forceinline__ void repack_one(
    const float* __restrict__ w, unsigned short* __restrict__ wp, int IC, int idx)
{
    int tap = idx % 9;
    int tmp = idx / 9;
    int ic  = tmp % IC;
    int oc  = tmp / IC;
    wp[oc * IC * 9 + (ic >> 6) * 576 + tap * 64 + (ic & 63)] = f2bs(w[idx]);
}
__global__ __launch_bounds__(256) void repack_all_kernel(
    const float* __restrict__ Wq, const float* __restrict__ Wkv,
    const float* __restrict__ Wout,
    unsigned short* __restrict__ wqb, unsigned short* __restrict__ wkvb,
    unsigned short* __restrict__ wopb)
{
    int idx = blockIdx.x * 256 + threadIdx.x;
    if (idx < 294912)        repack_one(Wq,   wqb,  64,  idx);
    else if (idx < 884736)   repack_one(Wkv,  wkvb, 64,  idx - 294912);
    else if (idx < 1179648)  repack_one(Wout, wopb, 512, idx - 884736);
}

// --------------------- standalone q conv (3x3, 64->512) --------------------
__global__ __launch_bounds__(512) void qconv_kernel(
    const unsigned short* __restrict__ qn,
    const unsigned short* __restrict__ wq,    // (512, 576) bf16
    unsigned short* __restrict__ qc)
{
    __shared__ __align__(16) unsigned short patch[100 * 88];
    const int tid = threadIdx.x, lane = tid & 63, w = tid >> 6;
    const int tx = blockIdx.x & 15, ty = blockIdx.x >> 4;
    const int img = blockIdx.y;
    const int gx0 = tx * 8 - 1, gy0 = ty * 8 - 1;
    const int r = lane & 15, kg = lane >> 4;
    const int m = w >> 1, nh = w & 1;

    for (int u = tid; u < 800; u += 512) {
        int pos = u >> 3, seg = u & 7;
        int hy = pos / 10, hx = pos - hy * 10;
        int gy = gy0 + hy, gx = gx0 + hx;
        uint4 v = make_uint4(0u, 0u, 0u, 0u);
        if ((unsigned)gy < 128u && (unsigned)gx < 128u)
            v = *reinterpret_cast<const uint4*>(
                qn + ((img * 128 + gy) * 128 + gx) * 64 + seg * 8);
        *reinterpret_cast<uint4*>(patch + pos * 88 + seg * 8) = v;
    }
    __syncthreads();

    f32x4 acc[16];
    #pragma unroll
    for (int n = 0; n < 16; ++n) acc[n] = f32x4{0.f, 0.f, 0.f, 0.f};

    #pragma unroll 2
    for (int kk = 0; kk < 18; ++kk) {
        int tap = kk >> 1, ic0 = (kk & 1) * 32;
        int ky = tap / 3, kx = tap - ky * 3;
        int pos = (m * 2 + (r >> 3) + ky) * 10 + (r & 7) + kx;
        bf16x8 a = *reinterpret_cast<const bf16x8*>(patch + pos * 88 + ic0 + kg * 8);
        #pragma unroll
        for (int n = 0; n < 16; ++n) {
            bf16x8 b = *reinterpret_cast<const bf16x8*>(
                wq + (size_t)(nh * 256 + n * 16 + r) * 576 + kk * 32 + kg * 8);
            acc[n] = __builtin_amdgcn_mfma_f32_16x16x32_bf16(a, b, acc[n], 0, 0, 0);
        }
    }
    #pragma unroll
    for (int n = 0; n < 16; ++n) {
        #pragma unroll
        for (int reg = 0; reg < 4; ++reg) {
            int p = m * 16 + kg * 4 + reg;
            int y = ty * 8 + (p >> 3), x = tx * 8 + (p & 7);
            qc[((size_t)(img * 128 + y) * 128 + x) * 512 + nh * 256 + n * 16 + r] =
                f2bs(0.125f * acc[n][reg]);
        }
    }
}

// ----------------- fused conv_kv + window attention ------------------------
// grid (1024, 2). 256 thr = 4 waves.  LDS 37,440 B -> 4 blocks/CU.
//   kvp   u16[3][36][88] @ 0      (19,008)   stride-88: ~2-way banks
//   kls   u16[48][72]    @ 19,008 ( 6,912)
//   vls_T u16[64][72]    @ 25,920 ( 9,216)  cols 48..63 zeroed once
//   pls   u16[16][72]    @ 35,136 ( 2,304)  cols 48..63 zeroed once
__global__ __launch_bounds__(256, 4) void fused_attn_kernel(
    const unsigned short* __restrict__ kvn,
    const unsigned short* __restrict__ wkv,
    const float* __restrict__ sa,
    unsigned short* __restrict__ qcao)
{
    __shared__ __align__(16) unsigned char smem[37440];
    unsigned short* kvp   = (unsigned short*)smem;
    unsigned short* kls   = (unsigned short*)(smem + 19008);
    unsigned short* vls_T = (unsigned short*)(smem + 25920);
    unsigned short* pls   = (unsigned short*)(smem + 35136);

    const int tid  = threadIdx.x;
    const int lane = tid & 63;
    const int w    = tid >> 6;
    const int wx = blockIdx.x & 31, wy = blockIdx.x >> 5;
    const int bb = blockIdx.y;
    const int gx0 = wx * 4 - 1, gy0 = wy * 4 - 1;

    // ---- stage kv halo patches (stride 88) ----
    for (int u = tid; u < 864; u += 256) {
        int f = u / 288, rest = u - f * 288;
        int pos = rest >> 3, seg = rest & 7;
        int hy = pos / 6, hx = pos - hy * 6;
        int gy = gy0 + hy, gx = gx0 + hx;
        uint4 v = make_uint4(0u, 0u, 0u, 0u);
        if ((unsigned)gy < 128u && (unsigned)gx < 128u)
            v = *reinterpret_cast<const uint4*>(
                kvn + (((bb * 3 + f) * 128 + gy) * 128 + gx) * 64 + seg * 8);
        *reinterpret_cast<uint4*>(kvp + (f * 36 + pos) * 88 + seg * 8) = v;
    }
    // ---- zero vls_T pad cols 48..63 ----
    for (int u = tid; u < 1024; u += 256) {
        int row = u >> 4, c = 48 + (u & 15);
        vls_T[row * 72 + c] = 0;
    }
    // ---- zero pls pad cols 48..63 (NaN x 0 = NaN) ----
    {
        int row = tid >> 4, c = 48 + (tid & 15);
        pls[row * 72 + c] = 0;
    }
    __syncthreads();

    const int r  = lane & 15;
    const int kg = lane >> 4;
    const int py = r >> 2, px = r & 3;
    const int is_v = w >> 1, pair = w & 1;

    const unsigned short* qbase =
        qcao + ((size_t)(bb * 128 + wy * 4 + (r >> 2)) * 128 + wx * 4 + (r & 3)) * 512;

    // prefetch q fragments for head 0
    bf16x8 qa0c = *reinterpret_cast<const bf16x8*>(qbase + kg * 8);
    bf16x8 qa1c = *reinterpret_cast<const bf16x8*>(qbase + 32 + kg * 8);
    bf16x8 qa0n = qa0c, qa1n = qa1c;

    f32x4 oacc = {0.f, 0.f, 0.f, 0.f};

    for (int h = 0; h < 8; ++h) {
        // ---- sa early-issue (consumed ~500cy later in softmax) ----
        float sav[4][3];
        #pragma unroll
        for (int reg = 0; reg < 4; ++reg)
            #pragma unroll
            for (int t = 0; t < 3; ++t)
                sav[reg][t] = sa[(h * 16 + kg * 4 + reg) * 48 + t * 16 + r];

        // ---- deferred ao write of head h-1 ----
        if (h > 0) {
            #pragma unroll
            for (int reg = 0; reg < 4; ++reg) {
                int i = kg * 4 + reg;
                int y = wy * 4 + (i >> 2), x = wx * 4 + (i & 3);
                qcao[((size_t)(bb * 128 + y) * 128 + x) * 512 + (h - 1) * 64 + w * 16 + r] =
                    f2bs(oacc[reg]);
            }
        }

        // ---- prefetch next head's q fragments (cols (h+1)*64: never written yet) ----
        if (h < 7) {
            qa0n = *reinterpret_cast<const bf16x8*>(qbase + (h + 1) * 64 + kg * 8);
            qa1n = *reinterpret_cast<const bf16x8*>(qbase + (h + 1) * 64 + 32 + kg * 8);
        }

        // ---- conv k,v for this head (depth-2 weight prefetch, static regs) ----
        {
            const int ocb = is_v * 512 + h * 64 + pair * 32;
            const unsigned short* wbr0 = wkv + (size_t)ocb * 576 + kg * 8 + (size_t)r * 576;
            const unsigned short* wbr1 = wbr0 + (size_t)16 * 576;
            bf16x8 bA0 = *reinterpret_cast<const bf16x8*>(wbr0);
            bf16x8 bA1 = *reinterpret_cast<const bf16x8*>(wbr1);
            bf16x8 bB0 = *reinterpret_cast<const bf16x8*>(wbr0 + 32);
            bf16x8 bB1 = *reinterpret_cast<const bf16x8*>(wbr1 + 32);
            f32x4 c00 = {0.f,0.f,0.f,0.f}, c01 = c00, c10 = c00, c11 = c00, c20 = c00, c21 = c00;
            #pragma unroll
            for (int kk2 = 0; kk2 < 18; kk2 += 2) {
                // even kk = kk2 (ic0 = 0), uses bA; prefetch kk2+2
                {
                    bf16x8 b0 = bA0, b1 = bA1;
                    if (kk2 + 2 < 18) {
                        bA0 = *reinterpret_cast<const bf16x8*>(wbr0 + (kk2 + 2) * 32);
                        bA1 = *reinterpret_cast<const bf16x8*>(wbr1 + (kk2 + 2) * 32);
                    }
                    int tap = kk2 >> 1;
                    int ky = tap / 3, kx = tap - ky * 3;
                    int pos = (py + ky) * 6 + (px + kx);
                    bf16x8 a0 = *reinterpret_cast<const bf16x8*>(kvp + pos * 88 + kg * 8);
                    bf16x8 a1 = *reinterpret_cast<const bf16x8*>(kvp + (36 + pos) * 88 + kg * 8);
                    bf16x8 a2 = *reinterpret_cast<const bf16x8*>(kvp + (72 + pos) * 88 + kg * 8);
                    c00 = __builtin_amdgcn_mfma_f32_16x16x32_bf16(a0, b0, c00, 0, 0, 0);
                    c10 = __builtin_amdgcn_mfma_f32_16x16x32_bf16(a1, b0, c10, 0, 0, 0);
                    c20 = __builtin_amdgcn_mfma_f32_16x16x32_bf16(a2, b0, c20, 0, 0, 0);
                    c01 = __builtin_amdgcn_mfma_f32_16x16x32_bf16(a0, b1, c01, 0, 0, 0);
                    c11 = __builtin_amdgcn_mfma_f32_16x16x32_bf16(a1, b1, c11, 0, 0, 0);
                    c21 = __builtin_amdgcn_mfma_f32_16x16x32_bf16(a2, b1, c21, 0, 0, 0);
                }
                // odd kk = kk2+1 (ic0 = 32), uses bB; prefetch kk2+3
                {
                    bf16x8 b0 = bB0, b1 = bB1;
                    if (kk2 + 3 < 18) {
                        bB0 = *reinterpret_cast<const bf16x8*>(wbr0 + (kk2 + 3) * 32);
                        bB1 = *reinterpret_cast<const bf16x8*>(wbr1 + (kk2 + 3) * 32);
                    }
                    int tap = kk2 >> 1;
                    int ky = tap / 3, kx = tap - ky * 3;
                    int pos = (py + ky) * 6 + (px + kx);
                    bf16x8 a0 = *reinterpret_cast<const bf16x8*>(kvp + pos * 88 + 32 + kg * 8);
                    bf16x8 a1 = *reinterpret_cast<const bf16x8*>(kvp + (36 + pos) * 88 + 32 + kg * 8);
                    bf16x8 a2 = *reinterpret_cast<const bf16x8*>(kvp + (72 + pos) * 88 + 32 + kg * 8);
                    c00 = __builtin_amdgcn_mfma_f32_16x16x32_bf16(a0, b0, c00, 0, 0, 0);
                    c10 = __builtin_amdgcn_mfma_f32_16x16x32_bf16(a1, b0, c10, 0, 0, 0);
                    c20 = __builtin_amdgcn_mfma_f32_16x16x32_bf16(a2, b0, c20, 0, 0, 0);
                    c01 = __builtin_amdgcn_mfma_f32_16x16x32_bf16(a0, b1, c01, 0, 0, 0);
                    c11 = __builtin_amdgcn_mfma_f32_16x16x32_bf16(a1, b1, c11, 0, 0, 0);
                    c21 = __builtin_amdgcn_mfma_f32_16x16x32_bf16(a2, b1, c21, 0, 0, 0);
                }
            }
            if (!is_v) {
                #pragma unroll
                for (int reg = 0; reg < 4; ++reg) {
                    int jr = kg * 4 + reg;
                    int cb = pair * 32 + r;
                    kls[(jr +  0) * 72 + cb]      = f2bs(c00[reg]);
                    kls[(jr + 16) * 72 + cb]      = f2bs(c10[reg]);
                    kls[(jr + 32) * 72 + cb]      = f2bs(c20[reg]);
                    kls[(jr +  0) * 72 + cb + 16] = f2bs(c01[reg]);
                    kls[(jr + 16) * 72 + cb + 16] = f2bs(c11[reg]);
                    kls[(jr + 32) * 72 + cb + 16] = f2bs(c21[reg]);
                }
            } else {
                #pragma unroll
                for (int reg = 0; reg < 4; ++reg) {
                    int jr = kg * 4 + reg;
                    int d0 = pair * 32 + r;
                    vls_T[d0 * 72        + jr]      = f2bs(c00[reg]);
                    vls_T[d0 * 72        + 16 + jr] = f2bs(c10[reg]);
                    vls_T[d0 * 72        + 32 + jr] = f2bs(c20[reg]);
                    vls_T[(d0 + 16) * 72 + jr]      = f2bs(c01[reg]);
                    vls_T[(d0 + 16) * 72 + 16 + jr] = f2bs(c11[reg]);
                    vls_T[(d0 + 16) * 72 + 32 + jr] = f2bs(c21[reg]);
                }
            }
        }
        __syncthreads();

        // ---- QK^T (redundant in all 4 waves) + in-register softmax ----
        {
            f32x4 s0 = {0.f,0.f,0.f,0.f}, s1 = s0, s2 = s0;
            #pragma unroll
            for (int t = 0; t < 3; ++t) {
                bf16x8 b0 = *reinterpret_cast<const bf16x8*>(kls + (t * 16 + r) * 72 + kg * 8);
                bf16x8 b1 = *reinterpret_cast<const bf16x8*>(kls + (t * 16 + r) * 72 + 32 + kg * 8);
                f32x4& st = (t == 0) ? s0 : (t == 1) ? s1 : s2;
                st = __builtin_amdgcn_mfma_f32_16x16x32_bf16(qa0c, b0, st, 0, 0, 0);
                st = __builtin_amdgcn_mfma_f32_16x16x32_bf16(qa1c, b1, st, 0, 0, 0);
            }
            #pragma unroll
            for (int reg = 0; reg < 4; ++reg) {
                int i = kg * 4 + reg;
                float v0 = s0[reg] + sav[reg][0];
                float v1 = s1[reg] + sav[reg][1];
                float v2 = s2[reg] + sav[reg][2];
                float mx = fmaxf(v0, fmaxf(v1, v2));
                #pragma unroll
                for (int m = 1; m < 16; m <<= 1) mx = fmaxf(mx, __shfl_xor(mx, m));
                float e0 = __expf(v0 - mx), e1 = __expf(v1 - mx), e2 = __expf(v2 - mx);
                float sum = e0 + e1 + e2;
                #pragma unroll
                for (int m = 1; m < 16; m <<= 1) sum += __shfl_xor(sum, m);
                float inv = 1.f / sum;
                pls[i * 72 + r]      = f2bs(e0 * inv);
                pls[i * 72 + 16 + r] = f2bs(e1 * inv);
                pls[i * 72 + 32 + r] = f2bs(e2 * inv);
            }
        }
        // own wave wrote every pls row it reads below.

        // ---- PV: wave w owns d-tile w ----
        {
            bf16x8 pa0 = *reinterpret_cast<const bf16x8*>(pls + r * 72 + kg * 8);
            bf16x8 pa1 = *reinterpret_cast<const bf16x8*>(pls + r * 72 + 32 + kg * 8);
            bf16x8 vb0 = *reinterpret_cast<const bf16x8*>(vls_T + (w * 16 + r) * 72 + kg * 8);
            bf16x8 vb1 = *reinterpret_cast<const bf16x8*>(vls_T + (w * 16 + r) * 72 + 32 + kg * 8);
            f32x4 o = {0.f, 0.f, 0.f, 0.f};
            o = __builtin_amdgcn_mfma_f32_16x16x32_bf16(pa0, vb0, o, 0, 0, 0);
            o = __builtin_amdgcn_mfma_f32_16x16x32_bf16(pa1, vb1, o, 0, 0, 0);
            oacc = o;
        }
        qa0c = qa0n; qa1c = qa1n;
        __syncthreads();
    }
    // ---- final head's output ----
    #pragma unroll
    for (int reg = 0; reg < 4; ++reg) {
        int i = kg * 4 + reg;
        int y = wy * 4 + (i >> 2), x = wx * 4 + (i & 3);
        qcao[((size_t)(bb * 128 + y) * 128 + x) * 512 + 7 * 64 + w * 16 + r] = f2bs(oacc[reg]);
    }
}

// --------------- 3x3 conv, IC=512 -> OC=64 via MFMA (out conv) -------------
__global__ __launch_bounds__(256) void conv512_kernel(
    const unsigned short* __restrict__ in,
    const unsigned short* __restrict__ wp,    // (64, 4608) bf16
    float* __restrict__ out)
{
    __shared__ __align__(16) unsigned short patch[100 * 88];
    const int tid = threadIdx.x, lane = tid & 63, w = tid >> 6;
    const int tx = blockIdx.x & 15, ty = blockIdx.x >> 4;
    const int img = blockIdx.y;
    const int gx0 = tx * 8 - 1, gy0 = ty * 8 - 1;
    const int r = lane & 15, kg = lane >> 6 == 0 ? lane >> 4 : lane >> 4;  // kg = lane>>4

    f32x4 acc0 = {0.f,0.f,0.f,0.f}, acc1 = acc0, acc2 = acc0, acc3 = acc0;
    const int oc = w * 16 + r;

    for (int ci = 0; ci < 8; ++ci) {
        __syncthreads();
        for (int u = tid; u < 800; u += 256) {
            int pos = u >> 3, seg = u & 7;
            int hy = pos / 10, hx = pos - hy * 10;
            int gy = gy0 + hy, gx = gx0 + hx;
            uint4 v = make_uint4(0u, 0u, 0u, 0u);
            if ((unsigned)gy < 128u && (unsigned)gx < 128u)
                v = *reinterpret_cast<const uint4*>(
                    in + (((size_t)img * 128 + gy) * 128 + gx) * 512 + ci * 64 + seg * 8);
            *reinterpret_cast<uint4*>(patch + pos * 88 + seg * 8) = v;
        }
        __syncthreads();
        const unsigned short* wb = wp + (size_t)oc * 4608 + ci * 576 + kg * 8;
        bf16x8 bA = *reinterpret_cast<const bf16x8*>(wb);
        bf16x8 bB = *reinterpret_cast<const bf16x8*>(wb + 32);
        #pragma unroll
        for (int kk2 = 0; kk2 < 18; kk2 += 2) {
            {
                bf16x8 b = bA;
                if (kk2 + 2 < 18) bA = *reinterpret_cast<const bf16x8*>(wb + (kk2 + 2) * 32);
                int tap = kk2 >> 1;
                int ky = tap / 3, kx = tap - ky * 3;
                #pragma unroll
                for (int m = 0; m < 4; ++m) {
                    int rr = m * 16 + r;
                    int pos = ((rr >> 3) + ky) * 10 + (rr & 7) + kx;
                    bf16x8 a = *reinterpret_cast<const bf16x8*>(patch + pos * 88 + kg * 8);
                    f32x4& acc = (m == 0) ? acc0 : (m == 1) ? acc1 : (m == 2) ? acc2 : acc3;
                    acc = __builtin_amdgcn_mfma_f32_16x16x32_bf16(a, b, acc, 0, 0, 0);
                }
            }
            {
                bf16x8 b = bB;
                if (kk2 + 3 < 18) bB = *reinterpret_cast<const bf16x8*>(wb + (kk2 + 3) * 32);
                int tap = kk2 >> 1;
                int ky = tap / 3, kx = tap - ky * 3;
                #pragma unroll
                for (int m = 0; m < 4; ++m) {
                    int rr = m * 16 + r;
                    int pos = ((rr >> 3) + ky) * 10 + (rr & 7) + kx;
                    bf16x8 a = *reinterpret_cast<const bf16x8*>(patch + pos * 88 + 32 + kg * 8);
                    f32x4& acc = (m == 0) ? acc0 : (m == 1) ? acc1 : (m == 2) ? acc2 : acc3;
                    acc = __builtin_amdgcn_mfma_f32_16x16x32_bf16(a, b, acc, 0, 0, 0);
                }
            }
        }
    }
    #pragma unroll
    for (int m = 0; m < 4; ++m) {
        const f32x4& acc = (m == 0) ? acc0 : (m == 1) ? acc1 : (m == 2) ? acc2 : acc3;
        int r0 = m * 16 + kg * 4;
        int gy = ty * 8 + (r0 >> 3), gx = tx * 8 + (r0 & 7);
        *reinterpret_cast<float4*>(
            out + (((size_t)img * 64 + oc) * 128 + gy) * 128 + gx) =
            make_float4(acc[0], acc[1], acc[2], acc[3]);
    }
}

// ---------------------------------------------------------------------------
extern "C" void kernel_launch(void* const* d_in, const int* in_sizes, int n_in,
                              void* d_out, int out_size, void* d_ws, size_t ws_size,
                              hipStream_t stream)
{
    const float* q_inp  = (const float*)d_in[0];
    const float* k_inp  = (const float*)d_in[1];
    const float* flow_f = (const float*)d_in[2];
    const float* flow_b = (const float*)d_in[3];
    const float* gq     = (const float*)d_in[4];
    const float* bq     = (const float*)d_in[5];
    const float* gkv    = (const float*)d_in[6];
    const float* bkv    = (const float*)d_in[7];
    const float* Wq     = (const float*)d_in[8];
    const float* Wkv    = (const float*)d_in[9];
    const float* Wout   = (const float*)d_in[10];
    const float* sa     = (const float*)d_in[11];

    if (ws_size < 55050240u) return;

    char* ws = (char*)d_ws;
    unsigned short* qn   = (unsigned short*)(ws + 0);
    unsigned short* kvn  = (unsigned short*)(ws + 4194304);
    unsigned short* qcao = (unsigned short*)(ws + 16777216);
    unsigned short* wqb  = (unsigned short*)(ws + 50331648);
    unsigned short* wkvb = (unsigned short*)(ws + 50921472);
    unsigned short* wopb = (unsigned short*)(ws + 52101120);

    ln_all_kernel<<<32768, 256, 0, stream>>>(q_inp, k_inp, flow_f, flow_b,
                                             gq, bq, gkv, bkv, qn, kvn);

    repack_all_kernel<<<4608, 256, 0, stream>>>(Wq, Wkv, Wout, wqb, wkvb, wopb);

    qconv_kernel<<<dim3(256, 2), 512, 0, stream>>>(qn, wqb, qcao);

    fused_attn_kernel<<<dim3(1024, 2), 256, 0, stream>>>(kvn, wkvb, sa, qcao);

    conv512_kernel<<<dim3(256, 2), 256, 0, stream>>>(qcao, wopb, (float*)d_out);
}

// Round 9
// 603.118 us; speedup vs baseline: 1.0318x; 1.0090x over previous
//
#include <hip/hip_runtime.h>

// ---------------------------------------------------------------------------
// FGSW-MSA, round 9 == round 8 (never ran: GPU acquisition timeout).
//  - transpose-first prologue. transpose_kernel: NCHW f32 -> NHWC f32
//    (q 2 imgs + k 6 imgs) into the qcao region (dead until qconv).
//    ln_fused_kernel then has fully coalesced reads (incl. warp gather).
//  - fused_attn: round-7 structure, but q-prefetch issued at END of conv
//    phase (vmcnt retires in-order; early HBM loads were chaining every
//    weight-load wait) and sa loaded directly in softmax.
//
// ws layout (bytes):
//   qn   (2,128,128,64)  bf16 @ 0           4,194,304
//   kvn  (6,128,128,64)  bf16 @ 4,194,304   12,582,912
//   qcao (2,128,128,512) bf16 @ 16,777,216  33,554,432  (transpose f32 scratch,
//                                                        then q-conv out == attn out)
//   wq   (512,576)  bf16      @ 50,331,648    589,824
//   wkv  (1024,576) bf16      @ 50,921,472  1,179,648
//   wop  (64,4608)  bf16      @ 52,101,120    589,824
// ---------------------------------------------------------------------------

typedef __attribute__((ext_vector_type(8))) short bf16x8;
typedef __attribute__((ext_vector_type(4))) float f32x4;

__device__ __forceinline__ float bs2f(unsigned short s) {
    return __uint_as_float(((unsigned int)s) << 16);
}
__device__ __forceinline__ unsigned short f2bs(float f) {
    unsigned int u = __float_as_uint(f);
    u += 0x7fffu + ((u >> 16) & 1u);   // RNE
    return (unsigned short)(u >> 16);
}

// ------------------- NCHW -> NHWC f32 transpose (q + k) --------------------
// grid (2 xtiles, 128 y, 8 img): img 0..1 = q_inp, img 2..7 = k_inp.
// out[img][y][x][c], 64x64 (x,c) tile per block via LDS.
__global__ __launch_bounds__(256) void transpose_kernel(
    const float* __restrict__ q_inp, const float* __restrict__ k_inp,
    float* __restrict__ t_out)
{
    __shared__ float tile[64][68];
    const int xt = blockIdx.x, y = blockIdx.y, img = blockIdx.z;
    const float* src = (img < 2) ? (q_inp + (size_t)img * 64 * 16384)
                                 : (k_inp + (size_t)(img - 2) * 64 * 16384);
    const int t = threadIdx.x;
    const int c = t >> 2, sub = t & 3;
    #pragma unroll
    for (int i = 0; i < 4; ++i) {
        int xl = sub * 16 + i * 4;
        float4 v = *reinterpret_cast<const float4*>(
            src + (size_t)c * 16384 + y * 128 + xt * 64 + xl);
        tile[xl + 0][c] = v.x;
        tile[xl + 1][c] = v.y;
        tile[xl + 2][c] = v.z;
        tile[xl + 3][c] = v.w;
    }
    __syncthreads();
    const int x = t >> 2, c4 = (t & 3) * 16;
    float* dst = t_out + ((size_t)img * 16384 + y * 128 + xt * 64 + x) * 64 + c4;
    #pragma unroll
    for (int i = 0; i < 4; ++i)
        *reinterpret_cast<float4*>(dst + i * 4) =
            *reinterpret_cast<const float4*>(&tile[x][c4 + i * 4]);
}

// --------- fused LayerNorm (q) + warp+LayerNorm (kv), NHWC reads -----------
// wid 0..32767: q path.  wid 32768..131071: kv path.
__global__ __launch_bounds__(256) void ln_fused_kernel(
    const float* __restrict__ t_nhwc,
    const float* __restrict__ flow_f, const float* __restrict__ flow_b,
    const float* __restrict__ gq, const float* __restrict__ bq,
    const float* __restrict__ gkv, const float* __restrict__ bkv,
    unsigned short* __restrict__ qn, unsigned short* __restrict__ kvn)
{
    int wid  = (blockIdx.x * 256 + threadIdx.x) >> 6;
    int lane = threadIdx.x & 63;
    float val, gg, bbv;
    unsigned short* dst;
    if (wid < 32768) {
        val = t_nhwc[(size_t)wid * 64 + lane];        // wid == img*16384 + pix
        gg = gq[lane]; bbv = bq[lane];
        dst = qn + (size_t)wid * 64 + lane;
    } else {
        int kw = wid - 32768;
        int x = kw & 127, y = (kw >> 7) & 127, bf = kw >> 14;
        int f = bf % 3, bb = bf / 3;
        int ix = x, iy = y;
        bool valid = true;
        if (f != 1) {
            const float* fl = (f == 0) ? flow_f : flow_b;
            float fx = fl[(bb * 2 + 0) * 16384 + y * 128 + x];
            float fy = fl[(bb * 2 + 1) * 16384 + y * 128 + x];
            ix = (int)rintf((float)x + fx);
            iy = (int)rintf((float)y + fy);
            valid = (ix >= 0 && ix < 128 && iy >= 0 && iy < 128);
        }
        val = valid ? t_nhwc[((size_t)(2 + bf) * 16384 + iy * 128 + ix) * 64 + lane] : 0.f;
        gg = gkv[lane]; bbv = bkv[lane];
        dst = kvn + (size_t)kw * 64 + lane;
    }
    float s = val;
    #pragma unroll
    for (int m = 1; m < 64; m <<= 1) s += __shfl_xor(s, m);
    float mu = s * (1.f / 64.f);
    float d = val - mu;
    float s2 = d * d;
    #pragma unroll
    for (int m = 1; m < 64; m <<= 1) s2 += __shfl_xor(s2, m);
    *dst = f2bs(d * rsqrtf(s2 * (1.f / 64.f) + 1e-5f) * gg + bbv);
}

// --------------------------- weight repack (all three) ---------------------
__device__ __forceinline__ void repack_one(
    const float* __restrict__ w, unsigned short* __restrict__ wp, int IC, int idx)
{
    int tap = idx % 9;
    int tmp = idx / 9;
    int ic  = tmp % IC;
    int oc  = tmp / IC;
    wp[oc * IC * 9 + (ic >> 6) * 576 + tap * 64 + (ic & 63)] = f2bs(w[idx]);
}
__global__ __launch_bounds__(256) void repack_all_kernel(
    const float* __restrict__ Wq, const float* __restrict__ Wkv,
    const float* __restrict__ Wout,
    unsigned short* __restrict__ wqb, unsigned short* __restrict__ wkvb,
    unsigned short* __restrict__ wopb)
{
    int idx = blockIdx.x * 256 + threadIdx.x;
    if (idx < 294912)        repack_one(Wq,   wqb,  64,  idx);
    else if (idx < 884736)   repack_one(Wkv,  wkvb, 64,  idx - 294912);
    else if (idx < 1179648)  repack_one(Wout, wopb, 512, idx - 884736);
}

// --------------------- standalone q conv (3x3, 64->512) --------------------
__global__ __launch_bounds__(512) void qconv_kernel(
    const unsigned short* __restrict__ qn,
    const unsigned short* __restrict__ wq,    // (512, 576) bf16
    unsigned short* __restrict__ qc)
{
    __shared__ __align__(16) unsigned short patch[100 * 88];
    const int tid = threadIdx.x, lane = tid & 63, w = tid >> 6;
    const int tx = blockIdx.x & 15, ty = blockIdx.x >> 4;
    const int img = blockIdx.y;
    const int gx0 = tx * 8 - 1, gy0 = ty * 8 - 1;
    const int r = lane & 15, kg = lane >> 4;
    const int m = w >> 1, nh = w & 1;

    for (int u = tid; u < 800; u += 512) {
        int pos = u >> 3, seg = u & 7;
        int hy = pos / 10, hx = pos - hy * 10;
        int gy = gy0 + hy, gx = gx0 + hx;
        uint4 v = make_uint4(0u, 0u, 0u, 0u);
        if ((unsigned)gy < 128u && (unsigned)gx < 128u)
            v = *reinterpret_cast<const uint4*>(
                qn + ((img * 128 + gy) * 128 + gx) * 64 + seg * 8);
        *reinterpret_cast<uint4*>(patch + pos * 88 + seg * 8) = v;
    }
    __syncthreads();

    f32x4 acc[16];
    #pragma unroll
    for (int n = 0; n < 16; ++n) acc[n] = f32x4{0.f, 0.f, 0.f, 0.f};

    #pragma unroll 2
    for (int kk = 0; kk < 18; ++kk) {
        int tap = kk >> 1, ic0 = (kk & 1) * 32;
        int ky = tap / 3, kx = tap - ky * 3;
        int pos = (m * 2 + (r >> 3) + ky) * 10 + (r & 7) + kx;
        bf16x8 a = *reinterpret_cast<const bf16x8*>(patch + pos * 88 + ic0 + kg * 8);
        #pragma unroll
        for (int n = 0; n < 16; ++n) {
            bf16x8 b = *reinterpret_cast<const bf16x8*>(
                wq + (size_t)(nh * 256 + n * 16 + r) * 576 + kk * 32 + kg * 8);
            acc[n] = __builtin_amdgcn_mfma_f32_16x16x32_bf16(a, b, acc[n], 0, 0, 0);
        }
    }
    #pragma unroll
    for (int n = 0; n < 16; ++n) {
        #pragma unroll
        for (int reg = 0; reg < 4; ++reg) {
            int p = m * 16 + kg * 4 + reg;
            int y = ty * 8 + (p >> 3), x = tx * 8 + (p & 7);
            qc[((size_t)(img * 128 + y) * 128 + x) * 512 + nh * 256 + n * 16 + r] =
                f2bs(0.125f * acc[n][reg]);
        }
    }
}

// ----------------- fused conv_kv + window attention ------------------------
// grid (1024, 2). 256 thr = 4 waves.  LDS 37,440 B -> 4 blocks/CU.
//   kvp   u16[3][36][88] @ 0      (19,008)
//   kls   u16[48][72]    @ 19,008 ( 6,912)
//   vls_T u16[64][72]    @ 25,920 ( 9,216)  cols 48..63 zeroed once
//   pls   u16[16][72]    @ 35,136 ( 2,304)  cols 48..63 zeroed once
__global__ __launch_bounds__(256, 4) void fused_attn_kernel(
    const unsigned short* __restrict__ kvn,
    const unsigned short* __restrict__ wkv,
    const float* __restrict__ sa,
    unsigned short* __restrict__ qcao)
{
    __shared__ __align__(16) unsigned char smem[37440];
    unsigned short* kvp   = (unsigned short*)smem;
    unsigned short* kls   = (unsigned short*)(smem + 19008);
    unsigned short* vls_T = (unsigned short*)(smem + 25920);
    unsigned short* pls   = (unsigned short*)(smem + 35136);

    const int tid  = threadIdx.x;
    const int lane = tid & 63;
    const int w    = tid >> 6;
    const int wx = blockIdx.x & 31, wy = blockIdx.x >> 5;
    const int bb = blockIdx.y;
    const int gx0 = wx * 4 - 1, gy0 = wy * 4 - 1;

    const int r  = lane & 15;
    const int kg = lane >> 4;

    const unsigned short* qbase =
        qcao + ((size_t)(bb * 128 + wy * 4 + (r >> 2)) * 128 + wx * 4 + (r & 3)) * 512;

    // head-0 q fragments: issue FIRST so they drain during staging + barrier.
    bf16x8 qa0c = *reinterpret_cast<const bf16x8*>(qbase + kg * 8);
    bf16x8 qa1c = *reinterpret_cast<const bf16x8*>(qbase + 32 + kg * 8);

    // ---- stage kv halo patches (stride 88) ----
    for (int u = tid; u < 864; u += 256) {
        int f = u / 288, rest = u - f * 288;
        int pos = rest >> 3, seg = rest & 7;
        int hy = pos / 6, hx = pos - hy * 6;
        int gy = gy0 + hy, gx = gx0 + hx;
        uint4 v = make_uint4(0u, 0u, 0u, 0u);
        if ((unsigned)gy < 128u && (unsigned)gx < 128u)
            v = *reinterpret_cast<const uint4*>(
                kvn + (((bb * 3 + f) * 128 + gy) * 128 + gx) * 64 + seg * 8);
        *reinterpret_cast<uint4*>(kvp + (f * 36 + pos) * 88 + seg * 8) = v;
    }
    // ---- zero vls_T pad cols 48..63 ----
    for (int u = tid; u < 1024; u += 256) {
        int row = u >> 4, c = 48 + (u & 15);
        vls_T[row * 72 + c] = 0;
    }
    // ---- zero pls pad cols 48..63 (NaN x 0 = NaN) ----
    {
        int row = tid >> 4, c = 48 + (tid & 15);
        pls[row * 72 + c] = 0;
    }
    __syncthreads();

    const int py = r >> 2, px = r & 3;
    const int is_v = w >> 1, pair = w & 1;

    bf16x8 qa0n = qa0c, qa1n = qa1c;
    f32x4 oacc = {0.f, 0.f, 0.f, 0.f};

    for (int h = 0; h < 8; ++h) {
        // ---- deferred ao write of head h-1 (store retires fast) ----
        if (h > 0) {
            #pragma unroll
            for (int reg = 0; reg < 4; ++reg) {
                int i = kg * 4 + reg;
                int y = wy * 4 + (i >> 2), x = wx * 4 + (i & 3);
                qcao[((size_t)(bb * 128 + y) * 128 + x) * 512 + (h - 1) * 64 + w * 16 + r] =
                    f2bs(oacc[reg]);
            }
        }

        // ---- conv k,v for this head (depth-2 weight prefetch, static regs) ----
        {
            const int ocb = is_v * 512 + h * 64 + pair * 32;
            const unsigned short* wbr0 = wkv + (size_t)ocb * 576 + kg * 8 + (size_t)r * 576;
            const unsigned short* wbr1 = wbr0 + (size_t)16 * 576;
            bf16x8 bA0 = *reinterpret_cast<const bf16x8*>(wbr0);
            bf16x8 bA1 = *reinterpret_cast<const bf16x8*>(wbr1);
            bf16x8 bB0 = *reinterpret_cast<const bf16x8*>(wbr0 + 32);
            bf16x8 bB1 = *reinterpret_cast<const bf16x8*>(wbr1 + 32);
            f32x4 c00 = {0.f,0.f,0.f,0.f}, c01 = c00, c10 = c00, c11 = c00, c20 = c00, c21 = c00;
            #pragma unroll
            for (int kk2 = 0; kk2 < 18; kk2 += 2) {
                {
                    bf16x8 b0 = bA0, b1 = bA1;
                    if (kk2 + 2 < 18) {
                        bA0 = *reinterpret_cast<const bf16x8*>(wbr0 + (kk2 + 2) * 32);
                        bA1 = *reinterpret_cast<const bf16x8*>(wbr1 + (kk2 + 2) * 32);
                    }
                    int tap = kk2 >> 1;
                    int ky = tap / 3, kx = tap - ky * 3;
                    int pos = (py + ky) * 6 + (px + kx);
                    bf16x8 a0 = *reinterpret_cast<const bf16x8*>(kvp + pos * 88 + kg * 8);
                    bf16x8 a1 = *reinterpret_cast<const bf16x8*>(kvp + (36 + pos) * 88 + kg * 8);
                    bf16x8 a2 = *reinterpret_cast<const bf16x8*>(kvp + (72 + pos) * 88 + kg * 8);
                    c00 = __builtin_amdgcn_mfma_f32_16x16x32_bf16(a0, b0, c00, 0, 0, 0);
                    c10 = __builtin_amdgcn_mfma_f32_16x16x32_bf16(a1, b0, c10, 0, 0, 0);
                    c20 = __builtin_amdgcn_mfma_f32_16x16x32_bf16(a2, b0, c20, 0, 0, 0);
                    c01 = __builtin_amdgcn_mfma_f32_16x16x32_bf16(a0, b1, c01, 0, 0, 0);
                    c11 = __builtin_amdgcn_mfma_f32_16x16x32_bf16(a1, b1, c11, 0, 0, 0);
                    c21 = __builtin_amdgcn_mfma_f32_16x16x32_bf16(a2, b1, c21, 0, 0, 0);
                }
                {
                    bf16x8 b0 = bB0, b1 = bB1;
                    if (kk2 + 3 < 18) {
                        bB0 = *reinterpret_cast<const bf16x8*>(wbr0 + (kk2 + 3) * 32);
                        bB1 = *reinterpret_cast<const bf16x8*>(wbr1 + (kk2 + 3) * 32);
                    }
                    int tap = kk2 >> 1;
                    int ky = tap / 3, kx = tap - ky * 3;
                    int pos = (py + ky) * 6 + (px + kx);
                    bf16x8 a0 = *reinterpret_cast<const bf16x8*>(kvp + pos * 88 + 32 + kg * 8);
                    bf16x8 a1 = *reinterpret_cast<const bf16x8*>(kvp + (36 + pos) * 88 + 32 + kg * 8);
                    bf16x8 a2 = *reinterpret_cast<const bf16x8*>(kvp + (72 + pos) * 88 + 32 + kg * 8);
                    c00 = __builtin_amdgcn_mfma_f32_16x16x32_bf16(a0, b0, c00, 0, 0, 0);
                    c10 = __builtin_amdgcn_mfma_f32_16x16x32_bf16(a1, b0, c10, 0, 0, 0);
                    c20 = __builtin_amdgcn_mfma_f32_16x16x32_bf16(a2, b0, c20, 0, 0, 0);
                    c01 = __builtin_amdgcn_mfma_f32_16x16x32_bf16(a0, b1, c01, 0, 0, 0);
                    c11 = __builtin_amdgcn_mfma_f32_16x16x32_bf16(a1, b1, c11, 0, 0, 0);
                    c21 = __builtin_amdgcn_mfma_f32_16x16x32_bf16(a2, b1, c21, 0, 0, 0);
                }
            }

            // ---- q prefetch for head h+1: issued AFTER all conv loads so the
            //      in-order vmcnt queue never forces conv waits behind HBM. ----
            if (h < 7) {
                qa0n = *reinterpret_cast<const bf16x8*>(qbase + (h + 1) * 64 + kg * 8);
                qa1n = *reinterpret_cast<const bf16x8*>(qbase + (h + 1) * 64 + 32 + kg * 8);
            }

            if (!is_v) {
                #pragma unroll
                for (int reg = 0; reg < 4; ++reg) {
                    int jr = kg * 4 + reg;
                    int cb = pair * 32 + r;
                    kls[(jr +  0) * 72 + cb]      = f2bs(c00[reg]);
                    kls[(jr + 16) * 72 + cb]      = f2bs(c10[reg]);
                    kls[(jr + 32) * 72 + cb]      = f2bs(c20[reg]);
                    kls[(jr +  0) * 72 + cb + 16] = f2bs(c01[reg]);
                    kls[(jr + 16) * 72 + cb + 16] = f2bs(c11[reg]);
                    kls[(jr + 32) * 72 + cb + 16] = f2bs(c21[reg]);
                }
            } else {
                #pragma unroll
                for (int reg = 0; reg < 4; ++reg) {
                    int jr = kg * 4 + reg;
                    int d0 = pair * 32 + r;
                    vls_T[d0 * 72        + jr]      = f2bs(c00[reg]);
                    vls_T[d0 * 72        + 16 + jr] = f2bs(c10[reg]);
                    vls_T[d0 * 72        + 32 + jr] = f2bs(c20[reg]);
                    vls_T[(d0 + 16) * 72 + jr]      = f2bs(c01[reg]);
                    vls_T[(d0 + 16) * 72 + 16 + jr] = f2bs(c11[reg]);
                    vls_T[(d0 + 16) * 72 + 32 + jr] = f2bs(c21[reg]);
                }
            }
        }
        __syncthreads();

        // ---- QK^T (redundant in all 4 waves) + in-register softmax ----
        {
            f32x4 s0 = {0.f,0.f,0.f,0.f}, s1 = s0, s2 = s0;
            #pragma unroll
            for (int t = 0; t < 3; ++t) {
                bf16x8 b0 = *reinterpret_cast<const bf16x8*>(kls + (t * 16 + r) * 72 + kg * 8);
                bf16x8 b1 = *reinterpret_cast<const bf16x8*>(kls + (t * 16 + r) * 72 + 32 + kg * 8);
                f32x4& st = (t == 0) ? s0 : (t == 1) ? s1 : s2;
                st = __builtin_amdgcn_mfma_f32_16x16x32_bf16(qa0c, b0, st, 0, 0, 0);
                st = __builtin_amdgcn_mfma_f32_16x16x32_bf16(qa1c, b1, st, 0, 0, 0);
            }
            #pragma unroll
            for (int reg = 0; reg < 4; ++reg) {
                int i = kg * 4 + reg;
                float v0 = s0[reg] + sa[(h * 16 + i) * 48 + r];
                float v1 = s1[reg] + sa[(h * 16 + i) * 48 + 16 + r];
                float v2 = s2[reg] + sa[(h * 16 + i) * 48 + 32 + r];
                float mx = fmaxf(v0, fmaxf(v1, v2));
                #pragma unroll
                for (int m = 1; m < 16; m <<= 1) mx = fmaxf(mx, __shfl_xor(mx, m));
                float e0 = __expf(v0 - mx), e1 = __expf(v1 - mx), e2 = __expf(v2 - mx);
                float sum = e0 + e1 + e2;
                #pragma unroll
                for (int m = 1; m < 16; m <<= 1) sum += __shfl_xor(sum, m);
                float inv = 1.f / sum;
                pls[i * 72 + r]      = f2bs(e0 * inv);
                pls[i * 72 + 16 + r] = f2bs(e1 * inv);
                pls[i * 72 + 32 + r] = f2bs(e2 * inv);
            }
        }
        // own wave wrote every pls row it reads below.

        // ---- PV: wave w owns d-tile w ----
        {
            bf16x8 pa0 = *reinterpret_cast<const bf16x8*>(pls + r * 72 + kg * 8);
            bf16x8 pa1 = *reinterpret_cast<const bf16x8*>(pls + r * 72 + 32 + kg * 8);
            bf16x8 vb0 = *reinterpret_cast<const bf16x8*>(vls_T + (w * 16 + r) * 72 + kg * 8);
            bf16x8 vb1 = *reinterpret_cast<const bf16x8*>(vls_T + (w * 16 + r) * 72 + 32 + kg * 8);
            f32x4 o = {0.f, 0.f, 0.f, 0.f};
            o = __builtin_amdgcn_mfma_f32_16x16x32_bf16(pa0, vb0, o, 0, 0, 0);
            o = __builtin_amdgcn_mfma_f32_16x16x32_bf16(pa1, vb1, o, 0, 0, 0);
            oacc = o;
        }
        qa0c = qa0n; qa1c = qa1n;
        __syncthreads();
    }
    // ---- final head's output ----
    #pragma unroll
    for (int reg = 0; reg < 4; ++reg) {
        int i = kg * 4 + reg;
        int y = wy * 4 + (i >> 2), x = wx * 4 + (i & 3);
        qcao[((size_t)(bb * 128 + y) * 128 + x) * 512 + 7 * 64 + w * 16 + r] = f2bs(oacc[reg]);
    }
}

// --------------- 3x3 conv, IC=512 -> OC=64 via MFMA (out conv) -------------
__global__ __launch_bounds__(256) void conv512_kernel(
    const unsigned short* __restrict__ in,
    const unsigned short* __restrict__ wp,    // (64, 4608) bf16
    float* __restrict__ out)
{
    __shared__ __align__(16) unsigned short patch[100 * 88];
    const int tid = threadIdx.x, lane = tid & 63, w = tid >> 6;
    const int tx = blockIdx.x & 15, ty = blockIdx.x >> 4;
    const int img = blockIdx.y;
    const int gx0 = tx * 8 - 1, gy0 = ty * 8 - 1;
    const int r = lane & 15, kg = lane >> 4;

    f32x4 acc0 = {0.f,0.f,0.f,0.f}, acc1 = acc0, acc2 = acc0, acc3 = acc0;
    const int oc = w * 16 + r;

    for (int ci = 0; ci < 8; ++ci) {
        __syncthreads();
        for (int u = tid; u < 800; u += 256) {
            int pos = u >> 3, seg = u & 7;
            int hy = pos / 10, hx = pos - hy * 10;
            int gy = gy0 + hy, gx = gx0 + hx;
            uint4 v = make_uint4(0u, 0u, 0u, 0u);
            if ((unsigned)gy < 128u && (unsigned)gx < 128u)
                v = *reinterpret_cast<const uint4*>(
                    in + (((size_t)img * 128 + gy) * 128 + gx) * 512 + ci * 64 + seg * 8);
            *reinterpret_cast<uint4*>(patch + pos * 88 + seg * 8) = v;
        }
        __syncthreads();
        const unsigned short* wb = wp + (size_t)oc * 4608 + ci * 576 + kg * 8;
        bf16x8 bA = *reinterpret_cast<const bf16x8*>(wb);
        bf16x8 bB = *reinterpret_cast<const bf16x8*>(wb + 32);
        #pragma unroll
        for (int kk2 = 0; kk2 < 18; kk2 += 2) {
            {
                bf16x8 b = bA;
                if (kk2 + 2 < 18) bA = *reinterpret_cast<const bf16x8*>(wb + (kk2 + 2) * 32);
                int tap = kk2 >> 1;
                int ky = tap / 3, kx = tap - ky * 3;
                #pragma unroll
                for (int m = 0; m < 4; ++m) {
                    int rr = m * 16 + r;
                    int pos = ((rr >> 3) + ky) * 10 + (rr & 7) + kx;
                    bf16x8 a = *reinterpret_cast<const bf16x8*>(patch + pos * 88 + kg * 8);
                    f32x4& acc = (m == 0) ? acc0 : (m == 1) ? acc1 : (m == 2) ? acc2 : acc3;
                    acc = __builtin_amdgcn_mfma_f32_16x16x32_bf16(a, b, acc, 0, 0, 0);
                }
            }
            {
                bf16x8 b = bB;
                if (kk2 + 3 < 18) bB = *reinterpret_cast<const bf16x8*>(wb + (kk2 + 3) * 32);
                int tap = kk2 >> 1;
                int ky = tap / 3, kx = tap - ky * 3;
                #pragma unroll
                for (int m = 0; m < 4; ++m) {
                    int rr = m * 16 + r;
                    int pos = ((rr >> 3) + ky) * 10 + (rr & 7) + kx;
                    bf16x8 a = *reinterpret_cast<const bf16x8*>(patch + pos * 88 + 32 + kg * 8);
                    f32x4& acc = (m == 0) ? acc0 : (m == 1) ? acc1 : (m == 2) ? acc2 : acc3;
                    acc = __builtin_amdgcn_mfma_f32_16x16x32_bf16(a, b, acc, 0, 0, 0);
                }
            }
        }
    }
    #pragma unroll
    for (int m = 0; m < 4; ++m) {
        const f32x4& acc = (m == 0) ? acc0 : (m == 1) ? acc1 : (m == 2) ? acc2 : acc3;
        int r0 = m * 16 + kg * 4;
        int gy = ty * 8 + (r0 >> 3), gx = tx * 8 + (r0 & 7);
        *reinterpret_cast<float4*>(
            out + (((size_t)img * 64 + oc) * 128 + gy) * 128 + gx) =
            make_float4(acc[0], acc[1], acc[2], acc[3]);
    }
}

// ---------------------------------------------------------------------------
extern "C" void kernel_launch(void* const* d_in, const int* in_sizes, int n_in,
                              void* d_out, int out_size, void* d_ws, size_t ws_size,
                              hipStream_t stream)
{
    const float* q_inp  = (const float*)d_in[0];
    const float* k_inp  = (const float*)d_in[1];
    const float* flow_f = (const float*)d_in[2];
    const float* flow_b = (const float*)d_in[3];
    const float* gq     = (const float*)d_in[4];
    const float* bq     = (const float*)d_in[5];
    const float* gkv    = (const float*)d_in[6];
    const float* bkv    = (const float*)d_in[7];
    const float* Wq     = (const float*)d_in[8];
    const float* Wkv    = (const float*)d_in[9];
    const float* Wout   = (const float*)d_in[10];
    const float* sa     = (const float*)d_in[11];

    if (ws_size < 55050240u) return;

    char* ws = (char*)d_ws;
    unsigned short* qn   = (unsigned short*)(ws + 0);
    unsigned short* kvn  = (unsigned short*)(ws + 4194304);
    unsigned short* qcao = (unsigned short*)(ws + 16777216);
    float*          tnh  = (float*)         (ws + 16777216);  // transpose scratch (dead before qconv)
    unsigned short* wqb  = (unsigned short*)(ws + 50331648);
    unsigned short* wkvb = (unsigned short*)(ws + 50921472);
    unsigned short* wopb = (unsigned short*)(ws + 52101120);

    transpose_kernel<<<dim3(2, 128, 8), 256, 0, stream>>>(q_inp, k_inp, tnh);

    ln_fused_kernel<<<32768, 256, 0, stream>>>(tnh, flow_f, flow_b,
                                               gq, bq, gkv, bkv, qn, kvn);

    repack_all_kernel<<<4608, 256, 0, stream>>>(Wq, Wkv, Wout, wqb, wkvb, wopb);

    qconv_kernel<<<dim3(256, 2), 512, 0, stream>>>(qn, wqb, qcao);

    fused_attn_kernel<<<dim3(1024, 2), 256, 0, stream>>>(kvn, wkvb, sa, qcao);

    conv512_kernel<<<dim3(256, 2), 256, 0, stream>>>(qcao, wopb, (float*)d_out);
}